// Round 10
// baseline (9505.016 us; speedup 1.0000x reference)
//
#include <hip/hip_runtime.h>

#define TC   50
#define BC   128
#define DXC  128
#define DYC  64
#define NMCC 100
#define XBS  136
#define A1S  136
#define A2S  72
#define A3S  40
#define IVS  72
#define KTS  72
#define HPS  20
#define LBS  12
#define ZSS  67
#define W2S  136
#define W3S  72

typedef float f32x4 __attribute__((ext_vector_type(4)));
typedef short s16x8 __attribute__((ext_vector_type(8)));

__device__ __forceinline__ unsigned short f2bf(float x){
  unsigned int u = __float_as_uint(x);
  u += 0x7fffu + ((u >> 16) & 1u);
  return (unsigned short)(u >> 16);
}

__device__ __forceinline__ unsigned int pk2bf(float lo, float hi){
  unsigned int r;
  asm volatile("v_cvt_pk_bf16_f32 %0, %1, %2" : "=v"(r) : "v"(lo), "v"(hi));
  return r;
}

__device__ __forceinline__ f32x4 mfma16(s16x8 a, s16x8 b, f32x4 c){
  return __builtin_amdgcn_mfma_f32_16x16x32_bf16(a, b, c, 0, 0, 0);
}

__device__ __forceinline__ s16x8 packA8(const float* p){
  f32x4 a = *(const f32x4*)p;
  f32x4 c = *(const f32x4*)(p + 4);
  s16x8 r;
  r[0]=(short)f2bf(a[0]); r[1]=(short)f2bf(a[1]);
  r[2]=(short)f2bf(a[2]); r[3]=(short)f2bf(a[3]);
  r[4]=(short)f2bf(c[0]); r[5]=(short)f2bf(c[1]);
  r[6]=(short)f2bf(c[2]); r[7]=(short)f2bf(c[3]);
  return r;
}

__device__ __forceinline__ float gc_taper(int row, int col){
  int dd = row - col; if (dd < 0) dd = -dd;
  if (128 - dd < dd) dd = 128 - dd;
  double z = (double)dd / 5.0;
  double g = 0.0;
  if (z < 1.0){
    g = 1.0 - (5.0/3.0)*z*z + (5.0/8.0)*z*z*z + 0.5*z*z*z*z - 0.25*z*z*z*z*z;
  } else if (z < 2.0){
    g = 4.0 - 5.0*z + (5.0/3.0)*z*z + (5.0/8.0)*z*z*z - 0.5*z*z*z*z
        + (1.0/12.0)*z*z*z*z*z - 2.0/(3.0*z);
  }
  return (float)(g / 99.0);
}

// ---------------- gin ----------------
__global__ __launch_bounds__(256) void gin_kernel(const float* __restrict__ obs,
                          const float* __restrict__ Wih, const float* __restrict__ bih,
                          float* __restrict__ gin){
  __shared__ float xrow[64];
  int blk = blockIdx.x;
  int t = blk / BC, b = blk % BC;
  int tid = threadIdx.x;
  if (tid < 64) xrow[tid] = obs[(b*TC + t)*DYC + tid];
  __syncthreads();
  float s = bih[tid];
  #pragma unroll
  for (int k = 0; k < 64; k += 4){
    f32x4 wv = *(const f32x4*)&Wih[tid*64 + k];
    s += wv[0]*xrow[k] + wv[1]*xrow[k+1] + wv[2]*xrow[k+2] + wv[3]*xrow[k+3];
  }
  gin[blk*256 + tid] = s;
}

// ---------------- lstm ----------------
__global__ __launch_bounds__(256,1) void lstm_kernel(const float* __restrict__ gin,
     const float* __restrict__ Whh,
     const float* __restrict__ Wm, const float* __restrict__ bm,
     const float* __restrict__ Wv, const float* __restrict__ bv,
     float* __restrict__ qmean, float* __restrict__ qstd, float* __restrict__ klp){
  __shared__ float h[64], cc[64], graw[256], red[128];
  int b = blockIdx.x, tid = threadIdx.x;
  float w[64];
  #pragma unroll
  for (int k = 0; k < 64; k += 4){
    f32x4 v = *(const f32x4*)&Whh[tid*64 + k];
    w[k]=v[0]; w[k+1]=v[1]; w[k+2]=v[2]; w[k+3]=v[3];
  }
  if (tid < 64){ h[tid] = 0.f; cc[tid] = 0.f; }
  __syncthreads();
  for (int t = 0; t < TC; ++t){
    float g = gin[(t*BC + b)*256 + tid];
    #pragma unroll
    for (int k = 0; k < 64; k += 4){
      f32x4 hv = *(const f32x4*)&h[k];
      g += hv[0]*w[k] + hv[1]*w[k+1] + hv[2]*w[k+2] + hv[3]*w[k+3];
    }
    graw[tid] = g;
    __syncthreads();
    if (tid < 64){
      float ig = 1.f/(1.f + expf(-graw[tid]));
      float fg = 1.f/(1.f + expf(-graw[64 + tid]));
      float gg = tanhf(graw[128 + tid]);
      float og = 1.f/(1.f + expf(-graw[192 + tid]));
      float cn = fg*cc[tid] + ig*gg;
      cc[tid] = cn;
      h[tid] = og*tanhf(cn);
    }
    __syncthreads();
  }
  if (tid < 128){
    float sm_ = bm[tid], sv_ = bv[tid];
    #pragma unroll
    for (int k = 0; k < 64; k += 4){
      f32x4 wmv = *(const f32x4*)&Wm[tid*64 + k];
      f32x4 wvv = *(const f32x4*)&Wv[tid*64 + k];
      f32x4 hv  = *(const f32x4*)&h[k];
      sm_ += wmv[0]*hv[0] + wmv[1]*hv[1] + wmv[2]*hv[2] + wmv[3]*hv[3];
      sv_ += wvv[0]*hv[0] + wvv[1]*hv[1] + wvv[2]*hv[2] + wvv[3]*hv[3];
    }
    float qv = ((sv_ > 20.f) ? sv_ : log1pf(expf(sv_))) + 1e-4f;
    qmean[b*DXC + tid] = sm_;
    qstd[b*DXC + tid]  = sqrtf(qv);
    red[tid] = 0.5f*(qv + sm_*sm_ - 1.f - logf(qv));
  }
  __syncthreads();
  if (tid == 0){
    float s = 0.f;
    for (int i = 0; i < 128; ++i) s += red[i];
    klp[b] = s;
  }
}

// ---------------- EnKF megakernel (R8 compute + phase timers) ----------------
__global__ __launch_bounds__(512,1) void enkf_kernel(
    const float* __restrict__ obs,
    const float* __restrict__ W1, const float* __restrict__ b1g,
    const float* __restrict__ W2, const float* __restrict__ b2g,
    const float* __restrict__ W3, const float* __restrict__ b3g,
    const float* __restrict__ W4, const float* __restrict__ b4g,
    const float* __restrict__ eps0, const float* __restrict__ epss,
    const float* __restrict__ nsyg,
    const float* __restrict__ qmean, const float* __restrict__ qstd,
    float* __restrict__ out_means, float* __restrict__ llp,
    unsigned long long* __restrict__ wsT)
{
  __shared__ unsigned short sU[128*XBS];
  __shared__ unsigned short sA[112*A1S];
  __shared__ unsigned short sB[112*A2S];
  __shared__ unsigned short sC[112*A3S];
  __shared__ unsigned short sW2[64*W2S];
  __shared__ unsigned short sW3[32*W3S];
  __shared__ float sHPb[64*HPS];
  __shared__ float sW9[9*12];
  __shared__ float sLb[64*LBS];
  __shared__ float sXm[DXC];
  __shared__ float sRv[DYC];
  __shared__ float sSc[4];

  const int b    = blockIdx.x;
  const int tid  = threadIdx.x;
  const int lane = tid & 63;
  const int wid  = tid >> 6;
  const int l15  = lane & 15;
  const int l4   = lane >> 4;

  const int colN = wid*16 + l15;
  const int rw   = wid;

  s16x8 w1f[4], w4f;
  #pragma unroll
  for (int kt = 0; kt < 4; ++kt) w1f[kt] = packA8(&W1[colN*128 + kt*32 + 8*l4]);
  w4f = packA8(&W4[colN*32 + 8*l4]);
  const float bb1 = b1g[colN], bb4 = b4g[colN];
  float bb2v[4], bb3v[2];
  #pragma unroll
  for (int cg = 0; cg < 4; ++cg) bb2v[cg] = b2g[cg*16 + l15];
  #pragma unroll
  for (int cg = 0; cg < 2; ++cg) bb3v[cg] = b3g[cg*16 + l15];

  const int mt1 = (0x22111000u >> (4*wid)) & 15;
  const int nt1 = (0x21210710u >> (4*wid)) & 15;
  const int mt2 = (0x3332u >> (4*wid)) & 15;
  const int nt2 = (0x4323u >> (4*wid)) & 15;
  float tv1[4], tv2[4];
  #pragma unroll
  for (int i = 0; i < 4; ++i){
    tv1[i] = gc_taper(mt1*16 + 4*l4 + i, nt1*16 + l15);
    tv2[i] = (wid < 4) ? gc_taper(mt2*16 + 4*l4 + i, nt2*16 + l15) : 0.f;
  }

  int cdk = 10, cdd = 0;
  { int acc = 0;
    #pragma unroll
    for (int q = 0; q < 10; ++q){
      int cnt = 10 - q;
      if (lane >= acc && lane < acc + cnt){ cdk = q; cdd = lane - acc; }
      acc += cnt;
    } }
  const int ioff_s  = (cdk + cdd > 9) ? 0 : (cdk + cdd);
  const int dk_s    = (cdk > 9) ? 0 : cdk;
  int baseNext = (cdk + 1)*10 - ((cdk + 1)*cdk)/2;
  const int shsrc   = (baseNext + cdd >= 55) ? 0 : (baseNext + cdd);
  const bool enterSlot = (cdk + cdd == 9) && (cdk <= 9);
  const bool isCol0    = (cdk == 0);

  for (int idx = tid; idx < 64*128; idx += 512)
    sW2[(idx >> 7)*W2S + (idx & 127)] = f2bf(W2[idx]);
  for (int idx = tid; idx < 32*64; idx += 512)
    sW3[(idx >> 6)*W3S + (idx & 63)] = f2bf(W3[idx]);

  float xreg[7][4];
  {
    float qm = qmean[b*DXC + colN], qs = qstd[b*DXC + colN];
    #pragma unroll
    for (int m = 0; m < 7; ++m)
      #pragma unroll
      for (int i = 0; i < 4; ++i){
        int row = m*16 + 4*l4 + i;
        float v = 0.f;
        if (row < NMCC) v = qm + qs * eps0[((size_t)row*BC + b)*DXC + colN];
        xreg[m][i] = v;
        if (row < NMCC) sU[row*XBS + colN] = f2bf(v);
      }
    for (int idx = tid; idx < 12*128; idx += 512)
      sU[(100 + (idx >> 7))*XBS + (idx & 127)] = 0;
  }
  __syncthreads();

  float llsum = 0.f;
  const f32x4 z4 = {0.f, 0.f, 0.f, 0.f};
  unsigned long long ph0=0, ph1=0, ph2=0, ph3=0, ph4=0, ph5=0, ph6=0;
  unsigned long long tprev = 0;
  if (tid == 0) tprev = clock64();

  for (int t = 0; t < TC; ++t){
    float ldet_t = 0.f;

    float y_r = 0.f, ypv = 0.f;
    if (wid < 4){
      y_r = obs[((size_t)b*TC + t)*DYC + colN];
      ypv = y_r + 0.1f*nsyg[((size_t)t*BC + b)*DYC + colN];
    }

    float ev[7][4];
    #pragma unroll
    for (int m = 0; m < 7; ++m)
      #pragma unroll
      for (int i = 0; i < 4; ++i){
        int row = m*16 + 4*l4 + i;
        ev[m][i] = (row < NMCC)
          ? epss[((size_t)(t*NMCC + row)*BC + b)*DXC + colN] : 0.f;
      }

    // ============ P1 ============
    {
      f32x4 acc[7];
      #pragma unroll
      for (int m = 0; m < 7; ++m) acc[m] = z4;
      #pragma unroll
      for (int kt = 0; kt < 4; ++kt){
        #pragma unroll
        for (int m = 0; m < 7; ++m){
          s16x8 af = *(const s16x8*)&sU[(m*16 + l15)*XBS + kt*32 + 8*l4];
          acc[m] = mfma16(af, w1f[kt], acc[m]);
        }
      }
      #pragma unroll
      for (int m = 0; m < 7; ++m)
        #pragma unroll
        for (int i = 0; i < 4; ++i){
          int row = m*16 + 4*l4 + i;
          sA[row*A1S + colN] = f2bf(fmaxf(acc[m][i] + bb1, 0.f));
        }
    }
    __syncthreads();
    if (tid == 0){ unsigned long long tn = clock64(); ph0 += tn - tprev; tprev = tn; }

    // ============ P2P3 fused ============
    if (rw < 7){
      f32x4 a2[4];
      #pragma unroll
      for (int cg = 0; cg < 4; ++cg) a2[cg] = z4;
      #pragma unroll
      for (int kt = 0; kt < 4; ++kt){
        s16x8 af = *(const s16x8*)&sA[(16*rw + l15)*A1S + kt*32 + 8*l4];
        #pragma unroll
        for (int cg = 0; cg < 4; ++cg){
          s16x8 bf = *(const s16x8*)&sW2[(cg*16 + l15)*W2S + kt*32 + 8*l4];
          a2[cg] = mfma16(af, bf, a2[cg]);
        }
      }
      #pragma unroll
      for (int cg = 0; cg < 4; ++cg)
        #pragma unroll
        for (int i = 0; i < 4; ++i){
          int row = 16*rw + 4*l4 + i;
          sB[row*A2S + cg*16 + l15] = f2bf(fmaxf(a2[cg][i] + bb2v[cg], 0.f));
        }
      f32x4 a3[2];
      a3[0] = z4; a3[1] = z4;
      #pragma unroll
      for (int kt = 0; kt < 2; ++kt){
        s16x8 af3 = *(const s16x8*)&sB[(16*rw + l15)*A2S + kt*32 + 8*l4];
        #pragma unroll
        for (int cg = 0; cg < 2; ++cg){
          s16x8 bf = *(const s16x8*)&sW3[(cg*16 + l15)*W3S + kt*32 + 8*l4];
          a3[cg] = mfma16(af3, bf, a3[cg]);
        }
      }
      #pragma unroll
      for (int cg = 0; cg < 2; ++cg)
        #pragma unroll
        for (int i = 0; i < 4; ++i){
          int row = 16*rw + 4*l4 + i;
          sC[row*A3S + cg*16 + l15] = f2bf(fmaxf(a3[cg][i] + bb3v[cg], 0.f));
        }
    }
    __syncthreads();
    if (tid == 0){ unsigned long long tn = clock64(); ph1 += tn - tprev; tprev = tn; }

    // ============ P4 ============
    {
      f32x4 acc[7];
      #pragma unroll
      for (int m = 0; m < 7; ++m) acc[m] = z4;
      #pragma unroll
      for (int m = 0; m < 7; ++m){
        s16x8 af = *(const s16x8*)&sC[(m*16 + l15)*A3S + 8*l4];
        acc[m] = mfma16(af, w4f, acc[m]);
      }
      float part = 0.f;
      #pragma unroll
      for (int m = 0; m < 7; ++m)
        #pragma unroll
        for (int i = 0; i < 4; ++i){
          int row = m*16 + 4*l4 + i;
          if (row < NMCC){
            float v = acc[m][i] + bb4 + 0.05f*ev[m][i];
            xreg[m][i] = v;
            part += v;
          } else xreg[m][i] = 0.f;
        }
      part += __shfl_xor(part, 16);
      part += __shfl_xor(part, 32);
      float xm = part * 0.01f;
      if (l4 == 0) sXm[colN] = xm;
      if (wid < 4 && l4 == 0) sRv[colN] = y_r - xm;

      if (colN <= 72 || colN >= 119){
        #pragma unroll
        for (int m = 0; m < 7; ++m){
          float v0, v1, v2, v3;
          if (m == 6 && l4 > 0){ v0 = v1 = v2 = v3 = 0.f; }
          else {
            v0 = xreg[m][0] - xm; v1 = xreg[m][1] - xm;
            v2 = xreg[m][2] - xm; v3 = xreg[m][3] - xm;
          }
          uint2 pk;
          pk.x = pk2bf(v0, v1);
          pk.y = pk2bf(v2, v3);
          *(uint2*)&sU[colN*XBS + m*16 + 4*l4] = pk;
        }
        uint2 zz; zz.x = 0u; zz.y = 0u;
        *(uint2*)&sU[colN*XBS + 112 + 4*l4] = zz;
      }
      if (wid == 0){
        #pragma unroll
        for (int m = 0; m < 7; ++m)
          #pragma unroll
          for (int i = 0; i < 4; ++i){
            int row = m*16 + 4*l4 + i;
            sB[row*IVS + colN] = (row < NMCC) ? f2bf(ypv - xreg[m][i])
                                              : (unsigned short)0;
          }
      }
    }
    __syncthreads();
    if (tid == 0){ unsigned long long tn = clock64(); ph2 += tn - tprev; tprev = tn; }

    // ============ P6 ============
    {
      f32x4 a1 = z4, a2 = z4;
      #pragma unroll
      for (int kt = 0; kt < 4; ++kt){
        s16x8 fa1 = *(const s16x8*)&sU[(mt1*16 + l15)*XBS + kt*32 + 8*l4];
        s16x8 fb1 = *(const s16x8*)&sU[(nt1*16 + l15)*XBS + kt*32 + 8*l4];
        a1 = mfma16(fa1, fb1, a1);
        if (wid < 4){
          s16x8 fa2 = *(const s16x8*)&sU[(mt2*16 + l15)*XBS + kt*32 + 8*l4];
          s16x8 fb2 = *(const s16x8*)&sU[(nt2*16 + l15)*XBS + kt*32 + 8*l4];
          a2 = mfma16(fa2, fb2, a2);
        }
      }
      #pragma unroll
      for (int i = 0; i < 4; ++i){
        int o = mt1*16 + 4*l4 + i, e = nt1*16 + l15;
        float v = a1[i] * tv1[i];
        if (nt1 != 7){
          int dd = e - o;
          if (dd >= -9 && dd <= 9) sHPb[o*HPS + dd + 9] = v;
        } else {
          int w = e - 119;
          if (w >= 0 && o <= w) sW9[o*12 + w] = v;
        }
      }
      if (wid < 4){
        #pragma unroll
        for (int i = 0; i < 4; ++i){
          int o = mt2*16 + 4*l4 + i, e = nt2*16 + l15;
          float v = a2[i] * tv2[i];
          int dd = e - o;
          if (dd >= -9 && dd <= 9) sHPb[o*HPS + dd + 9] = v;
        }
      }
    }
    __syncthreads();
    if (tid == 0){ unsigned long long tn = clock64(); ph3 += tn - tprev; tprev = tn; }

    // ============ P7: chol (w0) ∥ innov (w1-3) ∥ zero-K means (w4) ============
    if (wid == 0){
      __builtin_amdgcn_s_setprio(1);
      float v = 0.f;
      if (cdk <= 9) v = sHPb[cdk*HPS + cdd + 9] + ((cdd == 0) ? 0.01f : 0.f);
      for (int j = 0; j < 64; ++j){
        float enter = 0.f;
        if (enterSlot && (j + 10 < 64))
          enter = sHPb[(j + 10 - cdd)*HPS + cdd + 9] + ((cdd == 0) ? 0.01f : 0.f);
        float upiv = __uint_as_float(__builtin_amdgcn_readlane(__float_as_uint(v), 0));
        float u1   = __shfl(v, ioff_s);
        float u2   = __shfl(v, dk_s);
        float rd   = rsqrtf(upiv);
        float rpiv = rd * rd;
        if (isCol0){
          sLb[j*LBS + cdd] = (cdd == 0) ? rd : v * rd;
        }
        if (lane == 0) ldet_t += 0.5f * logf(upiv);
        float vu = (cdk >= 1) ? v - u1*u2*rpiv : v;
        float vs = __shfl(vu, shsrc);
        v = enterSlot ? enter : vs;
      }
      __builtin_amdgcn_s_setprio(0);
    } else if (wid < 4){
      #pragma unroll
      for (int m = 0; m < 7; ++m)
        #pragma unroll
        for (int i = 0; i < 4; ++i){
          int row = m*16 + 4*l4 + i;
          sB[row*IVS + colN] = (row < NMCC) ? f2bf(ypv - xreg[m][i])
                                            : (unsigned short)0;
        }
    } else if (wid == 4){
      if (lane < 46){
        int e = 73 + lane;
        out_means[((size_t)t*BC + b)*DXC + e] = sXm[e];
      }
    }
    __syncthreads();
    if (tid == 0){ unsigned long long tn = clock64(); ph4 += tn - tprev; tprev = tn; }

    // ============ P8: band solves (R8 1-deep prefetch) ============
    {
      float* zscr = (float*)sU;
      unsigned short* KT = (unsigned short*)sA;
      int c = tid;
      if (c < 83){
        int e = (c < 73) ? c : (c + 46);
        bool isr = (c == 82);
        float w0,w1,w2,w3,w4,w5,w6,w7,w8,w9;
        {
          float wi[10];
          #pragma unroll
          for (int d = 0; d < 10; ++d){
            float bv = 0.f;
            if (isr) bv = sRv[d];
            else if (c < 73){
              int idx = e - d + 9;
              if (idx >= 0 && idx <= 18) bv = sHPb[d*HPS + idx];
            } else {
              int ww = e - 119;
              if (d <= ww) bv = sW9[d*12 + ww];
            }
            wi[d] = bv;
          }
          w0=wi[0]; w1=wi[1]; w2=wi[2]; w3=wi[3]; w4=wi[4];
          w5=wi[5]; w6=wi[6]; w7=wi[7]; w8=wi[8]; w9=wi[9];
        }
        float z2l = 0.f;
        f32x4 lb0 = *(const f32x4*)&sLb[0];
        f32x4 lb4 = *(const f32x4*)&sLb[4];
        float2 l89 = *(const float2*)&sLb[8];
        for (int j = 0; j < 64; ++j){
          f32x4 nb0 = lb0, nb4 = lb4; float2 n89 = l89;
          if (j + 1 < 64){
            nb0 = *(const f32x4*)&sLb[(j+1)*LBS];
            nb4 = *(const f32x4*)&sLb[(j+1)*LBS + 4];
            n89 = *(const float2*)&sLb[(j+1)*LBS + 8];
          }
          float z = w0 * lb0[0];
          zscr[c*ZSS + j] = z;
          z2l += z*z;
          w0 = w1 - lb0[1]*z; w1 = w2 - lb0[2]*z; w2 = w3 - lb0[3]*z;
          w3 = w4 - lb4[0]*z; w4 = w5 - lb4[1]*z; w5 = w6 - lb4[2]*z;
          w6 = w7 - lb4[3]*z; w7 = w8 - l89.x*z;  w8 = w9 - l89.y*z;
          int jn = j + 10;
          float bv = 0.f;
          if (isr){ if (jn < 64) bv = sRv[jn]; }
          else if (c < 73){
            if (jn < 64 && j >= e - 19 && j <= e - 1) bv = sHPb[jn*HPS + (e - j - 1)];
          }
          w9 = bv;
          lb0 = nb0; lb4 = nb4; l89 = n89;
        }
        if (isr) sSc[0] = z2l;
        float x1=0.f,x2=0.f,x3=0.f,x4=0.f,x5=0.f,x6=0.f,x7=0.f,x8=0.f,x9=0.f;
        float macc = 0.f, xodd = 0.f;
        lb0 = *(const f32x4*)&sLb[63*LBS];
        lb4 = *(const f32x4*)&sLb[63*LBS + 4];
        l89 = *(const float2*)&sLb[63*LBS + 8];
        float zcur = zscr[c*ZSS + 63];
        for (int j = 63; j >= 0; --j){
          f32x4 nb0 = lb0, nb4 = lb4; float2 n89 = l89;
          float znext = zcur;
          if (j > 0){
            nb0 = *(const f32x4*)&sLb[(j-1)*LBS];
            nb4 = *(const f32x4*)&sLb[(j-1)*LBS + 4];
            n89 = *(const float2*)&sLb[(j-1)*LBS + 8];
            znext = zscr[c*ZSS + j - 1];
          }
          float acc = zcur
            - lb0[1]*x1 - lb0[2]*x2 - lb0[3]*x3
            - lb4[0]*x4 - lb4[1]*x5 - lb4[2]*x6 - lb4[3]*x7
            - l89.x*x8 - l89.y*x9;
          float xj = acc * lb0[0];
          if (!isr){
            macc += sRv[j]*xj;
            if (j & 1) xodd = xj;
            else *(unsigned int*)&KT[e*KTS + j] = pk2bf(xj, xodd);
          }
          x9=x8; x8=x7; x7=x6; x6=x5; x5=x4; x4=x3; x3=x2; x2=x1; x1=xj;
          lb0 = nb0; lb4 = nb4; l89 = n89; zcur = znext;
        }
        if (!isr) out_means[((size_t)t*BC + b)*DXC + e] = sXm[e] + macc;
      }
    }
    __syncthreads();
    if (tid == 0){ unsigned long long tn = clock64(); ph5 += tn - tprev; tprev = tn; }

    // ============ P10 ============
    if (tid == 0){
      llsum += -0.5f*sSc[0] - ldet_t - 58.812066f;
    }
    {
      f32x4 uacc[7];
      #pragma unroll
      for (int m = 0; m < 7; ++m) uacc[m] = z4;
      if (wid != 5 && wid != 6){
        const unsigned short* KT = (const unsigned short*)sA;
        #pragma unroll
        for (int kt = 0; kt < 2; ++kt){
          s16x8 bf = *(const s16x8*)&KT[colN*KTS + kt*32 + 8*l4];
          #pragma unroll
          for (int m = 0; m < 7; ++m){
            s16x8 af = *(const s16x8*)&sB[(m*16 + l15)*IVS + kt*32 + 8*l4];
            uacc[m] = mfma16(af, bf, uacc[m]);
          }
        }
      }
      bool upd = ((colN <= 72) || (colN >= 119)) && (wid != 5) && (wid != 6);
      #pragma unroll
      for (int m = 0; m < 7; ++m)
        #pragma unroll
        for (int i = 0; i < 4; ++i){
          int row = m*16 + 4*l4 + i;
          if (row < NMCC){
            float xn = xreg[m][i] + (upd ? uacc[m][i] : 0.f);
            xreg[m][i] = xn;
            sU[row*XBS + colN] = f2bf(xn);
          }
        }
    }
    __syncthreads();
    if (tid == 0){ unsigned long long tn = clock64(); ph6 += tn - tprev; tprev = tn; }
  } // t loop

  if (tid == 0) llp[b] = llsum;
  if (b == 0 && tid == 0){
    wsT[0] = ph0; wsT[1] = ph1; wsT[2] = ph2; wsT[3] = ph3;
    wsT[4] = ph4; wsT[5] = ph5; wsT[6] = ph6;
  }
}

// ---------------- spin probes: duration = 4 x phase cycles (cap 5 ms) ----------------
#define SPIN_KERNEL(NAME, IDX)                                          \
__global__ void NAME(const unsigned long long* __restrict__ wsT){       \
  unsigned long long target = wsT[IDX] * 4ull;                          \
  if (target > 12000000ull) target = 12000000ull;                       \
  long long t0 = clock64();                                             \
  while ((unsigned long long)(clock64() - t0) < target){ }              \
}
SPIN_KERNEL(sp_p1,    0)
SPIN_KERNEL(sp_p23,   1)
SPIN_KERNEL(sp_p4,    2)
SPIN_KERNEL(sp_p6,    3)
SPIN_KERNEL(sp_chol,  4)
SPIN_KERNEL(sp_solve, 5)
SPIN_KERNEL(sp_upd,   6)

// ---------------- final ----------------
__global__ void final_kernel(const float* __restrict__ klp, const float* __restrict__ llp,
                             float* __restrict__ out){
  __shared__ float s1[128], s2[128];
  int tid = threadIdx.x;
  s1[tid] = klp[tid];
  s2[tid] = llp[tid];
  __syncthreads();
  if (tid == 0){
    float a = 0.f, c = 0.f;
    for (int i = 0; i < 128; ++i){ a += s1[i]; c += s2[i]; }
    out[0] = -a/128.f + c/128.f;
  }
}

extern "C" void kernel_launch(void* const* d_in, const int* in_sizes, int n_in,
                              void* d_out, int out_size, void* d_ws, size_t ws_size,
                              hipStream_t stream){
  (void)in_sizes; (void)n_in; (void)out_size; (void)ws_size;
  const float* obs  = (const float*)d_in[0];
  const float* W1   = (const float*)d_in[1];
  const float* b1   = (const float*)d_in[2];
  const float* W2   = (const float*)d_in[3];
  const float* b2   = (const float*)d_in[4];
  const float* W3   = (const float*)d_in[5];
  const float* b3   = (const float*)d_in[6];
  const float* W4   = (const float*)d_in[7];
  const float* b4   = (const float*)d_in[8];
  const float* Wih  = (const float*)d_in[9];
  const float* Whh  = (const float*)d_in[10];
  const float* bih  = (const float*)d_in[11];
  const float* Wm   = (const float*)d_in[12];
  const float* bm   = (const float*)d_in[13];
  const float* Wv   = (const float*)d_in[14];
  const float* bv   = (const float*)d_in[15];
  const float* eps0 = (const float*)d_in[16];
  const float* epss = (const float*)d_in[17];
  const float* nsy  = (const float*)d_in[18];

  char* ws = (char*)d_ws;
  float* gin   = (float*)(ws + 0);
  float* qmean = (float*)(ws + 6553600);
  float* qstd  = (float*)(ws + 6619136);
  float* klp   = (float*)(ws + 6684672);
  float* llp   = (float*)(ws + 6685184);
  unsigned long long* wsT = (unsigned long long*)(ws + 6686208);

  float* out = (float*)d_out;

  hipLaunchKernelGGL(gin_kernel, dim3(TC*BC), dim3(256), 0, stream,
                     obs, Wih, bih, gin);
  hipLaunchKernelGGL(lstm_kernel, dim3(BC), dim3(256), 0, stream,
                     gin, Whh, Wm, bm, Wv, bv, qmean, qstd, klp);
  hipLaunchKernelGGL(enkf_kernel, dim3(BC), dim3(512), 0, stream,
                     obs, W1, b1, W2, b2, W3, b3, W4, b4,
                     eps0, epss, nsy, qmean, qstd, out + 1, llp, wsT);
  hipLaunchKernelGGL(sp_p1,    dim3(1), dim3(64), 0, stream, wsT);
  hipLaunchKernelGGL(sp_p23,   dim3(1), dim3(64), 0, stream, wsT);
  hipLaunchKernelGGL(sp_p4,    dim3(1), dim3(64), 0, stream, wsT);
  hipLaunchKernelGGL(sp_p6,    dim3(1), dim3(64), 0, stream, wsT);
  hipLaunchKernelGGL(sp_chol,  dim3(1), dim3(64), 0, stream, wsT);
  hipLaunchKernelGGL(sp_solve, dim3(1), dim3(64), 0, stream, wsT);
  hipLaunchKernelGGL(sp_upd,   dim3(1), dim3(64), 0, stream, wsT);
  hipLaunchKernelGGL(final_kernel, dim3(1), dim3(128), 0, stream, klp, llp, out);
}

// Round 11
// 1759.532 us; speedup vs baseline: 5.4020x; 5.4020x over previous
//
#include <hip/hip_runtime.h>

#define TC   50
#define BC   128
#define DXC  128
#define DYC  64
#define NMCC 100
#define XBS  136
#define A1S  136
#define A2S  72
#define A3S  40
#define IVS  72
#define KTS  72
#define HPS  20
#define LBS  12
#define ZSS  67
#define W2S  136
#define W3S  72

typedef float f32x4 __attribute__((ext_vector_type(4)));
typedef short s16x8 __attribute__((ext_vector_type(8)));

__device__ __forceinline__ unsigned short f2bf(float x){
  unsigned int u = __float_as_uint(x);
  u += 0x7fffu + ((u >> 16) & 1u);
  return (unsigned short)(u >> 16);
}

__device__ __forceinline__ unsigned int pk2bf(float lo, float hi){
  unsigned int r;
  asm volatile("v_cvt_pk_bf16_f32 %0, %1, %2" : "=v"(r) : "v"(lo), "v"(hi));
  return r;
}

__device__ __forceinline__ f32x4 mfma16(s16x8 a, s16x8 b, f32x4 c){
  return __builtin_amdgcn_mfma_f32_16x16x32_bf16(a, b, c, 0, 0, 0);
}

__device__ __forceinline__ s16x8 packA8(const float* p){
  f32x4 a = *(const f32x4*)p;
  f32x4 c = *(const f32x4*)(p + 4);
  s16x8 r;
  r[0]=(short)f2bf(a[0]); r[1]=(short)f2bf(a[1]);
  r[2]=(short)f2bf(a[2]); r[3]=(short)f2bf(a[3]);
  r[4]=(short)f2bf(c[0]); r[5]=(short)f2bf(c[1]);
  r[6]=(short)f2bf(c[2]); r[7]=(short)f2bf(c[3]);
  return r;
}

__device__ __forceinline__ float gc_taper(int row, int col){
  int dd = row - col; if (dd < 0) dd = -dd;
  if (128 - dd < dd) dd = 128 - dd;
  double z = (double)dd / 5.0;
  double g = 0.0;
  if (z < 1.0){
    g = 1.0 - (5.0/3.0)*z*z + (5.0/8.0)*z*z*z + 0.5*z*z*z*z - 0.25*z*z*z*z*z;
  } else if (z < 2.0){
    g = 4.0 - 5.0*z + (5.0/3.0)*z*z + (5.0/8.0)*z*z*z - 0.5*z*z*z*z
        + (1.0/12.0)*z*z*z*z*z - 2.0/(3.0*z);
  }
  return (float)(g / 99.0);
}

// ---------------- gin ----------------
__global__ __launch_bounds__(256) void gin_kernel(const float* __restrict__ obs,
                          const float* __restrict__ Wih, const float* __restrict__ bih,
                          float* __restrict__ gin){
  __shared__ float xrow[64];
  int blk = blockIdx.x;
  int t = blk / BC, b = blk % BC;
  int tid = threadIdx.x;
  if (tid < 64) xrow[tid] = obs[(b*TC + t)*DYC + tid];
  __syncthreads();
  float s = bih[tid];
  #pragma unroll
  for (int k = 0; k < 64; k += 4){
    f32x4 wv = *(const f32x4*)&Wih[tid*64 + k];
    s += wv[0]*xrow[k] + wv[1]*xrow[k+1] + wv[2]*xrow[k+2] + wv[3]*xrow[k+3];
  }
  gin[blk*256 + tid] = s;
}

// ---------------- lstm ----------------
__global__ __launch_bounds__(256,1) void lstm_kernel(const float* __restrict__ gin,
     const float* __restrict__ Whh,
     const float* __restrict__ Wm, const float* __restrict__ bm,
     const float* __restrict__ Wv, const float* __restrict__ bv,
     float* __restrict__ qmean, float* __restrict__ qstd, float* __restrict__ klp){
  __shared__ float h[64], cc[64], graw[256], red[128];
  int b = blockIdx.x, tid = threadIdx.x;
  float w[64];
  #pragma unroll
  for (int k = 0; k < 64; k += 4){
    f32x4 v = *(const f32x4*)&Whh[tid*64 + k];
    w[k]=v[0]; w[k+1]=v[1]; w[k+2]=v[2]; w[k+3]=v[3];
  }
  if (tid < 64){ h[tid] = 0.f; cc[tid] = 0.f; }
  __syncthreads();
  for (int t = 0; t < TC; ++t){
    float g = gin[(t*BC + b)*256 + tid];
    #pragma unroll
    for (int k = 0; k < 64; k += 4){
      f32x4 hv = *(const f32x4*)&h[k];
      g += hv[0]*w[k] + hv[1]*w[k+1] + hv[2]*w[k+2] + hv[3]*w[k+3];
    }
    graw[tid] = g;
    __syncthreads();
    if (tid < 64){
      float ig = 1.f/(1.f + expf(-graw[tid]));
      float fg = 1.f/(1.f + expf(-graw[64 + tid]));
      float gg = tanhf(graw[128 + tid]);
      float og = 1.f/(1.f + expf(-graw[192 + tid]));
      float cn = fg*cc[tid] + ig*gg;
      cc[tid] = cn;
      h[tid] = og*tanhf(cn);
    }
    __syncthreads();
  }
  if (tid < 128){
    float sm_ = bm[tid], sv_ = bv[tid];
    #pragma unroll
    for (int k = 0; k < 64; k += 4){
      f32x4 wmv = *(const f32x4*)&Wm[tid*64 + k];
      f32x4 wvv = *(const f32x4*)&Wv[tid*64 + k];
      f32x4 hv  = *(const f32x4*)&h[k];
      sm_ += wmv[0]*hv[0] + wmv[1]*hv[1] + wmv[2]*hv[2] + wmv[3]*hv[3];
      sv_ += wvv[0]*hv[0] + wvv[1]*hv[1] + wvv[2]*hv[2] + wvv[3]*hv[3];
    }
    float qv = ((sv_ > 20.f) ? sv_ : log1pf(expf(sv_))) + 1e-4f;
    qmean[b*DXC + tid] = sm_;
    qstd[b*DXC + tid]  = sqrtf(qv);
    red[tid] = 0.5f*(qv + sm_*sm_ - 1.f - logf(qv));
  }
  __syncthreads();
  if (tid == 0){
    float s = 0.f;
    for (int i = 0; i < 128; ++i) s += red[i];
    klp[b] = s;
  }
}

// ---------------- EnKF megakernel: wave-parallel solves fused with update ----------------
__global__ __launch_bounds__(512,1) void enkf_kernel(
    const float* __restrict__ obs,
    const float* __restrict__ W1, const float* __restrict__ b1g,
    const float* __restrict__ W2, const float* __restrict__ b2g,
    const float* __restrict__ W3, const float* __restrict__ b3g,
    const float* __restrict__ W4, const float* __restrict__ b4g,
    const float* __restrict__ eps0, const float* __restrict__ epss,
    const float* __restrict__ nsyg,
    const float* __restrict__ qmean, const float* __restrict__ qstd,
    float* __restrict__ out_means, float* __restrict__ llp)
{
  __shared__ unsigned short sU[128*XBS];   // Xbf [112][136] / XcT [128][136]
  __shared__ unsigned short sA[112*A1S];   // acts1 / KT
  __shared__ unsigned short sB[112*A2S];   // acts2 / innov
  __shared__ unsigned short sC[112*A3S];   // acts3
  __shared__ unsigned short sW2[64*W2S];
  __shared__ unsigned short sW3[32*W3S];
  __shared__ float sHPb[64*HPS];
  __shared__ float sW9[9*12];
  __shared__ float sLb[64*LBS];
  __shared__ float sZ[83*ZSS];             // z scratch (dedicated, 22 KB)
  __shared__ float sXm[DXC];
  __shared__ float sRv[DYC];
  __shared__ float sSc[4];

  const int b    = blockIdx.x;
  const int tid  = threadIdx.x;
  const int lane = tid & 63;
  const int wid  = tid >> 6;
  const int l15  = lane & 15;
  const int l4   = lane >> 4;

  const int colN = wid*16 + l15;
  const int rw   = wid;

  s16x8 w1f[4], w4f;
  #pragma unroll
  for (int kt = 0; kt < 4; ++kt) w1f[kt] = packA8(&W1[colN*128 + kt*32 + 8*l4]);
  w4f = packA8(&W4[colN*32 + 8*l4]);
  const float bb1 = b1g[colN], bb4 = b4g[colN];
  float bb2v[4], bb3v[2];
  #pragma unroll
  for (int cg = 0; cg < 4; ++cg) bb2v[cg] = b2g[cg*16 + l15];
  #pragma unroll
  for (int cg = 0; cg < 2; ++cg) bb3v[cg] = b3g[cg*16 + l15];

  const int mt1 = (0x22111000u >> (4*wid)) & 15;
  const int nt1 = (0x21210710u >> (4*wid)) & 15;
  const int mt2 = (0x3332u >> (4*wid)) & 15;
  const int nt2 = (0x4323u >> (4*wid)) & 15;
  float tv1[4], tv2[4];
  #pragma unroll
  for (int i = 0; i < 4; ++i){
    tv1[i] = gc_taper(mt1*16 + 4*l4 + i, nt1*16 + l15);
    tv2[i] = (wid < 4) ? gc_taper(mt2*16 + 4*l4 + i, nt2*16 + l15) : 0.f;
  }

  int cdk = 10, cdd = 0;
  { int acc = 0;
    #pragma unroll
    for (int q = 0; q < 10; ++q){
      int cnt = 10 - q;
      if (lane >= acc && lane < acc + cnt){ cdk = q; cdd = lane - acc; }
      acc += cnt;
    } }
  const int ioff_s  = (cdk + cdd > 9) ? 0 : (cdk + cdd);
  const int dk_s    = (cdk > 9) ? 0 : cdk;
  int baseNext = (cdk + 1)*10 - ((cdk + 1)*cdk)/2;
  const int shsrc   = (baseNext + cdd >= 55) ? 0 : (baseNext + cdd);
  const bool enterSlot = (cdk + cdd == 9) && (cdk <= 9);
  const bool isCol0    = (cdk == 0);

  for (int idx = tid; idx < 64*128; idx += 512)
    sW2[(idx >> 7)*W2S + (idx & 127)] = f2bf(W2[idx]);
  for (int idx = tid; idx < 32*64; idx += 512)
    sW3[(idx >> 6)*W3S + (idx & 63)] = f2bf(W3[idx]);

  float xreg[7][4];
  {
    float qm = qmean[b*DXC + colN], qs = qstd[b*DXC + colN];
    #pragma unroll
    for (int m = 0; m < 7; ++m)
      #pragma unroll
      for (int i = 0; i < 4; ++i){
        int row = m*16 + 4*l4 + i;
        float v = 0.f;
        if (row < NMCC) v = qm + qs * eps0[((size_t)row*BC + b)*DXC + colN];
        xreg[m][i] = v;
        if (row < NMCC) sU[row*XBS + colN] = f2bf(v);
      }
    for (int idx = tid; idx < 12*128; idx += 512)
      sU[(100 + (idx >> 7))*XBS + (idx & 127)] = 0;
  }
  __syncthreads();

  float llsum = 0.f;
  float pldet = 0.f;
  const f32x4 z4 = {0.f, 0.f, 0.f, 0.f};

  for (int t = 0; t < TC; ++t){
    // ll carry from previous step (sSc stable: last written pre-barrier of t-1)
    if (tid == 0 && t > 0)
      llsum += -0.5f*sSc[0] - pldet - 58.812066f;

    float y_r = 0.f, ypv = 0.f;
    if (wid < 4){
      y_r = obs[((size_t)b*TC + t)*DYC + colN];
      ypv = y_r + 0.1f*nsyg[((size_t)t*BC + b)*DYC + colN];
    }

    float ev[7][4];
    #pragma unroll
    for (int m = 0; m < 7; ++m)
      #pragma unroll
      for (int i = 0; i < 4; ++i){
        int row = m*16 + 4*l4 + i;
        ev[m][i] = (row < NMCC)
          ? epss[((size_t)(t*NMCC + row)*BC + b)*DXC + colN] : 0.f;
      }

    // ============ P1: MLP L1 ============
    {
      f32x4 acc[7];
      #pragma unroll
      for (int m = 0; m < 7; ++m) acc[m] = z4;
      #pragma unroll
      for (int kt = 0; kt < 4; ++kt){
        #pragma unroll
        for (int m = 0; m < 7; ++m){
          s16x8 af = *(const s16x8*)&sU[(m*16 + l15)*XBS + kt*32 + 8*l4];
          acc[m] = mfma16(af, w1f[kt], acc[m]);
        }
      }
      #pragma unroll
      for (int m = 0; m < 7; ++m)
        #pragma unroll
        for (int i = 0; i < 4; ++i){
          int row = m*16 + 4*l4 + i;
          sA[row*A1S + colN] = f2bf(fmaxf(acc[m][i] + bb1, 0.f));
        }
    }
    __syncthreads();

    // ============ P2P3: fused L2+L3 (row-scheme) ============
    if (rw < 7){
      f32x4 a2[4];
      #pragma unroll
      for (int cg = 0; cg < 4; ++cg) a2[cg] = z4;
      #pragma unroll
      for (int kt = 0; kt < 4; ++kt){
        s16x8 af = *(const s16x8*)&sA[(16*rw + l15)*A1S + kt*32 + 8*l4];
        #pragma unroll
        for (int cg = 0; cg < 4; ++cg){
          s16x8 bf = *(const s16x8*)&sW2[(cg*16 + l15)*W2S + kt*32 + 8*l4];
          a2[cg] = mfma16(af, bf, a2[cg]);
        }
      }
      #pragma unroll
      for (int cg = 0; cg < 4; ++cg)
        #pragma unroll
        for (int i = 0; i < 4; ++i){
          int row = 16*rw + 4*l4 + i;
          sB[row*A2S + cg*16 + l15] = f2bf(fmaxf(a2[cg][i] + bb2v[cg], 0.f));
        }
      f32x4 a3[2];
      a3[0] = z4; a3[1] = z4;
      #pragma unroll
      for (int kt = 0; kt < 2; ++kt){
        s16x8 af3 = *(const s16x8*)&sB[(16*rw + l15)*A2S + kt*32 + 8*l4];
        #pragma unroll
        for (int cg = 0; cg < 2; ++cg){
          s16x8 bf = *(const s16x8*)&sW3[(cg*16 + l15)*W3S + kt*32 + 8*l4];
          a3[cg] = mfma16(af3, bf, a3[cg]);
        }
      }
      #pragma unroll
      for (int cg = 0; cg < 2; ++cg)
        #pragma unroll
        for (int i = 0; i < 4; ++i){
          int row = 16*rw + 4*l4 + i;
          sC[row*A3S + cg*16 + l15] = f2bf(fmaxf(a3[cg][i] + bb3v[cg], 0.f));
        }
    }
    __syncthreads();

    // ============ P4: L4 + eps -> xreg; mean; XcT; rv; innov(w0) ============
    {
      f32x4 acc[7];
      #pragma unroll
      for (int m = 0; m < 7; ++m) acc[m] = z4;
      #pragma unroll
      for (int m = 0; m < 7; ++m){
        s16x8 af = *(const s16x8*)&sC[(m*16 + l15)*A3S + 8*l4];
        acc[m] = mfma16(af, w4f, acc[m]);
      }
      float part = 0.f;
      #pragma unroll
      for (int m = 0; m < 7; ++m)
        #pragma unroll
        for (int i = 0; i < 4; ++i){
          int row = m*16 + 4*l4 + i;
          if (row < NMCC){
            float v = acc[m][i] + bb4 + 0.05f*ev[m][i];
            xreg[m][i] = v;
            part += v;
          } else xreg[m][i] = 0.f;
        }
      part += __shfl_xor(part, 16);
      part += __shfl_xor(part, 32);
      float xm = part * 0.01f;
      if (l4 == 0) sXm[colN] = xm;
      if (wid < 4 && l4 == 0) sRv[colN] = y_r - xm;

      if (colN <= 72 || colN >= 119){
        #pragma unroll
        for (int m = 0; m < 7; ++m){
          float v0, v1, v2, v3;
          if (m == 6 && l4 > 0){ v0 = v1 = v2 = v3 = 0.f; }
          else {
            v0 = xreg[m][0] - xm; v1 = xreg[m][1] - xm;
            v2 = xreg[m][2] - xm; v3 = xreg[m][3] - xm;
          }
          uint2 pk;
          pk.x = pk2bf(v0, v1);
          pk.y = pk2bf(v2, v3);
          *(uint2*)&sU[colN*XBS + m*16 + 4*l4] = pk;
        }
        uint2 zz; zz.x = 0u; zz.y = 0u;
        *(uint2*)&sU[colN*XBS + 112 + 4*l4] = zz;
      }
      if (wid == 0){
        #pragma unroll
        for (int m = 0; m < 7; ++m)
          #pragma unroll
          for (int i = 0; i < 4; ++i){
            int row = m*16 + 4*l4 + i;
            sB[row*IVS + colN] = (row < NMCC) ? f2bf(ypv - xreg[m][i])
                                              : (unsigned short)0;
          }
      }
    }
    __syncthreads();

    // ============ P6: banded cov ============
    {
      f32x4 a1 = z4, a2 = z4;
      #pragma unroll
      for (int kt = 0; kt < 4; ++kt){
        s16x8 fa1 = *(const s16x8*)&sU[(mt1*16 + l15)*XBS + kt*32 + 8*l4];
        s16x8 fb1 = *(const s16x8*)&sU[(nt1*16 + l15)*XBS + kt*32 + 8*l4];
        a1 = mfma16(fa1, fb1, a1);
        if (wid < 4){
          s16x8 fa2 = *(const s16x8*)&sU[(mt2*16 + l15)*XBS + kt*32 + 8*l4];
          s16x8 fb2 = *(const s16x8*)&sU[(nt2*16 + l15)*XBS + kt*32 + 8*l4];
          a2 = mfma16(fa2, fb2, a2);
        }
      }
      #pragma unroll
      for (int i = 0; i < 4; ++i){
        int o = mt1*16 + 4*l4 + i, e = nt1*16 + l15;
        float v = a1[i] * tv1[i];
        if (nt1 != 7){
          int dd = e - o;
          if (dd >= -9 && dd <= 9) sHPb[o*HPS + dd + 9] = v;
        } else {
          int w = e - 119;
          if (w >= 0 && o <= w) sW9[o*12 + w] = v;
        }
      }
      if (wid < 4){
        #pragma unroll
        for (int i = 0; i < 4; ++i){
          int o = mt2*16 + 4*l4 + i, e = nt2*16 + l15;
          float v = a2[i] * tv2[i];
          int dd = e - o;
          if (dd >= -9 && dd <= 9) sHPb[o*HPS + dd + 9] = v;
        }
      }
    }
    __syncthreads();

    // ============ P7: chol (w0) ∥ innov (w1-3) ∥ zero-K means (w4) ============
    if (wid == 0){
      __builtin_amdgcn_s_setprio(1);
      float v = 0.f;
      if (cdk <= 9) v = sHPb[cdk*HPS + cdd + 9] + ((cdd == 0) ? 0.01f : 0.f);
      for (int j = 0; j < 64; ++j){
        float enter = 0.f;
        if (enterSlot && (j + 10 < 64))
          enter = sHPb[(j + 10 - cdd)*HPS + cdd + 9] + ((cdd == 0) ? 0.01f : 0.f);
        float upiv = __uint_as_float(__builtin_amdgcn_readlane(__float_as_uint(v), 0));
        float u1   = __shfl(v, ioff_s);
        float u2   = __shfl(v, dk_s);
        float rd   = rsqrtf(upiv);
        float rpiv = rd * rd;
        if (isCol0){
          sLb[j*LBS + cdd] = (cdd == 0) ? rd : v * rd;
        }
        if (lane == 0) pldet = (j == 0 ? 0.f : pldet) + 0.5f * logf(upiv);
        float vu = (cdk >= 1) ? v - u1*u2*rpiv : v;
        float vs = __shfl(vu, shsrc);
        v = enterSlot ? enter : vs;
      }
      __builtin_amdgcn_s_setprio(0);
    } else if (wid < 4){
      #pragma unroll
      for (int m = 0; m < 7; ++m)
        #pragma unroll
        for (int i = 0; i < 4; ++i){
          int row = m*16 + 4*l4 + i;
          sB[row*IVS + colN] = (row < NMCC) ? f2bf(ypv - xreg[m][i])
                                            : (unsigned short)0;
        }
    } else if (wid == 4){
      if (lane < 46){
        int e = 73 + lane;
        out_means[((size_t)t*BC + b)*DXC + e] = sXm[e];
      }
    }
    __syncthreads();

    // ============ FUSED P8+P10: per-wave solves -> own KT -> own update ============
    {
      unsigned short* KT = (unsigned short*)sA;   // acts1 dead

      if (wid <= 4){
        // linear columns e = 16w + lane (wave 4: 9 cols)
        const int E0   = 16*wid;
        const int nact = (wid == 4) ? 9 : 16;
        const int j0w  = (E0 >= 9) ? (E0 - 9) : 0;
        int jR = E0 + 14; if (jR > 53) jR = 53;   // last refill iter
        if (jR < j0w) jR = j0w - 1;
        if (lane < nact){
          const int e = E0 + lane;
          float w0,w1,w2,w3,w4,w5,w6,w7,w8,w9;
          {
            float wi[10];
            #pragma unroll
            for (int d = 0; d < 10; ++d){
              int row = j0w + d;
              int idx = e - row + 9;
              wi[d] = (row < 64 && idx >= 0 && idx <= 18)
                      ? sHPb[row*HPS + idx] : 0.f;
            }
            w0=wi[0]; w1=wi[1]; w2=wi[2]; w3=wi[3]; w4=wi[4];
            w5=wi[5]; w6=wi[6]; w7=wi[7]; w8=wi[8]; w9=wi[9];
          }
          // forward A: refill zone
          for (int j = j0w; j <= jR; ++j){
            f32x4 lb0 = *(const f32x4*)&sLb[j*LBS];
            f32x4 lb4 = *(const f32x4*)&sLb[j*LBS + 4];
            float2 l89 = *(const float2*)&sLb[j*LBS + 8];
            float z = w0 * lb0[0];
            sZ[e*ZSS + j] = z;
            w0 = w1 - lb0[1]*z; w1 = w2 - lb0[2]*z; w2 = w3 - lb0[3]*z;
            w3 = w4 - lb4[0]*z; w4 = w5 - lb4[1]*z; w5 = w6 - lb4[2]*z;
            w6 = w7 - lb4[3]*z; w7 = w8 - l89.x*z;  w8 = w9 - l89.y*z;
            w9 = (j >= e - 19 && j <= e - 1) ? sHPb[(j+10)*HPS + (e - j - 1)] : 0.f;
          }
          // forward B: zero refill
          for (int j = jR + 1; j < 64; ++j){
            f32x4 lb0 = *(const f32x4*)&sLb[j*LBS];
            f32x4 lb4 = *(const f32x4*)&sLb[j*LBS + 4];
            float2 l89 = *(const float2*)&sLb[j*LBS + 8];
            float z = w0 * lb0[0];
            sZ[e*ZSS + j] = z;
            w0 = w1 - lb0[1]*z; w1 = w2 - lb0[2]*z; w2 = w3 - lb0[3]*z;
            w3 = w4 - lb4[0]*z; w4 = w5 - lb4[1]*z; w5 = w6 - lb4[2]*z;
            w6 = w7 - lb4[3]*z; w7 = w8 - l89.x*z;  w8 = w9 - l89.y*z;
            w9 = 0.f;
          }
          // backward C: with z reads (j >= j0w)
          float x1=0.f,x2=0.f,x3=0.f,x4=0.f,x5=0.f,x6=0.f,x7=0.f,x8=0.f,x9=0.f;
          float macc = 0.f, xodd = 0.f;
          for (int j = 63; j >= j0w; --j){
            f32x4 lb0 = *(const f32x4*)&sLb[j*LBS];
            f32x4 lb4 = *(const f32x4*)&sLb[j*LBS + 4];
            float2 l89 = *(const float2*)&sLb[j*LBS + 8];
            float acc = sZ[e*ZSS + j]
              - lb0[1]*x1 - lb0[2]*x2 - lb0[3]*x3
              - lb4[0]*x4 - lb4[1]*x5 - lb4[2]*x6 - lb4[3]*x7
              - l89.x*x8 - l89.y*x9;
            float xj = acc * lb0[0];
            macc += sRv[j]*xj;
            if (j & 1) xodd = xj;
            else *(unsigned int*)&KT[e*KTS + j] = pk2bf(xj, xodd);
            x9=x8; x8=x7; x7=x6; x6=x5; x5=x4; x4=x3; x3=x2; x2=x1; x1=xj;
          }
          // backward D: z = 0 zone
          for (int j = j0w - 1; j >= 0; --j){
            f32x4 lb0 = *(const f32x4*)&sLb[j*LBS];
            f32x4 lb4 = *(const f32x4*)&sLb[j*LBS + 4];
            float2 l89 = *(const float2*)&sLb[j*LBS + 8];
            float acc =
              - lb0[1]*x1 - lb0[2]*x2 - lb0[3]*x3
              - lb4[0]*x4 - lb4[1]*x5 - lb4[2]*x6 - lb4[3]*x7
              - l89.x*x8 - l89.y*x9;
            float xj = acc * lb0[0];
            macc += sRv[j]*xj;
            if (j & 1) xodd = xj;
            else *(unsigned int*)&KT[e*KTS + j] = pk2bf(xj, xodd);
            x9=x8; x8=x7; x7=x6; x6=x5; x5=x4; x4=x3; x3=x2; x2=x1; x1=xj;
          }
          out_means[((size_t)t*BC + b)*DXC + e] = sXm[e] + macc;
        }
        if (wid == 4 && lane >= 9 && lane < 16){
          int e = 64 + lane;                      // 73..79: zero KT rows
          #pragma unroll
          for (int k = 0; k < 64; k += 8){
            uint4 zz; zz.x = zz.y = zz.z = zz.w = 0u;
            *(uint4*)&KT[e*KTS + k] = zz;
          }
        }
      } else if (wid == 7){
        if (lane < 9){
          const int e = 119 + lane;
          const int slot = 73 + lane;
          float w0,w1,w2,w3,w4,w5,w6,w7,w8,w9;
          {
            float wi[10];
            #pragma unroll
            for (int d = 0; d < 10; ++d)
              wi[d] = (d <= lane) ? sW9[d*12 + lane] : 0.f;
            w0=wi[0]; w1=wi[1]; w2=wi[2]; w3=wi[3]; w4=wi[4];
            w5=wi[5]; w6=wi[6]; w7=wi[7]; w8=wi[8]; w9=wi[9];
          }
          for (int j = 0; j < 64; ++j){
            f32x4 lb0 = *(const f32x4*)&sLb[j*LBS];
            f32x4 lb4 = *(const f32x4*)&sLb[j*LBS + 4];
            float2 l89 = *(const float2*)&sLb[j*LBS + 8];
            float z = w0 * lb0[0];
            sZ[slot*ZSS + j] = z;
            w0 = w1 - lb0[1]*z; w1 = w2 - lb0[2]*z; w2 = w3 - lb0[3]*z;
            w3 = w4 - lb4[0]*z; w4 = w5 - lb4[1]*z; w5 = w6 - lb4[2]*z;
            w6 = w7 - lb4[3]*z; w7 = w8 - l89.x*z;  w8 = w9 - l89.y*z;
            w9 = 0.f;
          }
          float x1=0.f,x2=0.f,x3=0.f,x4=0.f,x5=0.f,x6=0.f,x7=0.f,x8=0.f,x9=0.f;
          float macc = 0.f, xodd = 0.f;
          for (int j = 63; j >= 0; --j){
            f32x4 lb0 = *(const f32x4*)&sLb[j*LBS];
            f32x4 lb4 = *(const f32x4*)&sLb[j*LBS + 4];
            float2 l89 = *(const float2*)&sLb[j*LBS + 8];
            float acc = sZ[slot*ZSS + j]
              - lb0[1]*x1 - lb0[2]*x2 - lb0[3]*x3
              - lb4[0]*x4 - lb4[1]*x5 - lb4[2]*x6 - lb4[3]*x7
              - l89.x*x8 - l89.y*x9;
            float xj = acc * lb0[0];
            macc += sRv[j]*xj;
            if (j & 1) xodd = xj;
            else *(unsigned int*)&KT[e*KTS + j] = pk2bf(xj, xodd);
            x9=x8; x8=x7; x7=x6; x6=x5; x5=x4; x4=x3; x3=x2; x2=x1; x1=xj;
          }
          out_means[((size_t)t*BC + b)*DXC + e] = sXm[e] + macc;
        }
        if (lane >= 9 && lane < 16){
          int e = 103 + lane;                     // 112..118: zero KT rows
          #pragma unroll
          for (int k = 0; k < 64; k += 8){
            uint4 zz; zz.x = zz.y = zz.z = zz.w = 0u;
            *(uint4*)&KT[e*KTS + k] = zz;
          }
        }
      } else if (wid == 6){
        if (lane == 0){
          // rv column: forward only -> z2l
          float w0,w1,w2,w3,w4,w5,w6,w7,w8,w9;
          w0=sRv[0]; w1=sRv[1]; w2=sRv[2]; w3=sRv[3]; w4=sRv[4];
          w5=sRv[5]; w6=sRv[6]; w7=sRv[7]; w8=sRv[8]; w9=sRv[9];
          float z2l = 0.f;
          for (int j = 0; j < 64; ++j){
            f32x4 lb0 = *(const f32x4*)&sLb[j*LBS];
            f32x4 lb4 = *(const f32x4*)&sLb[j*LBS + 4];
            float2 l89 = *(const float2*)&sLb[j*LBS + 8];
            float z = w0 * lb0[0];
            z2l += z*z;
            w0 = w1 - lb0[1]*z; w1 = w2 - lb0[2]*z; w2 = w3 - lb0[3]*z;
            w3 = w4 - lb4[0]*z; w4 = w5 - lb4[1]*z; w5 = w6 - lb4[2]*z;
            w6 = w7 - lb4[3]*z; w7 = w8 - l89.x*z;  w8 = w9 - l89.y*z;
            w9 = (j + 10 < 64) ? sRv[j + 10] : 0.f;
          }
          sSc[0] = z2l;
        }
      }

      // ---- own-KT update (no barrier: wave reads only its own KT rows) ----
      f32x4 uacc[7];
      #pragma unroll
      for (int m = 0; m < 7; ++m) uacc[m] = z4;
      if (wid != 5 && wid != 6){
        #pragma unroll
        for (int kt = 0; kt < 2; ++kt){
          s16x8 bf = *(const s16x8*)&KT[colN*KTS + kt*32 + 8*l4];
          #pragma unroll
          for (int m = 0; m < 7; ++m){
            s16x8 af = *(const s16x8*)&sB[(m*16 + l15)*IVS + kt*32 + 8*l4];
            uacc[m] = mfma16(af, bf, uacc[m]);
          }
        }
      }
      #pragma unroll
      for (int m = 0; m < 7; ++m)
        #pragma unroll
        for (int i = 0; i < 4; ++i){
          int row = m*16 + 4*l4 + i;
          if (row < NMCC){
            float xn = xreg[m][i] + uacc[m][i];
            xreg[m][i] = xn;
            sU[row*XBS + colN] = f2bf(xn);
          }
        }
    }
    __syncthreads();
  } // t loop

  if (tid == 0){
    llsum += -0.5f*sSc[0] - pldet - 58.812066f;   // last step
    llp[b] = llsum;
  }
}

// ---------------- final ----------------
__global__ void final_kernel(const float* __restrict__ klp, const float* __restrict__ llp,
                             float* __restrict__ out){
  __shared__ float s1[128], s2[128];
  int tid = threadIdx.x;
  s1[tid] = klp[tid];
  s2[tid] = llp[tid];
  __syncthreads();
  if (tid == 0){
    float a = 0.f, c = 0.f;
    for (int i = 0; i < 128; ++i){ a += s1[i]; c += s2[i]; }
    out[0] = -a/128.f + c/128.f;
  }
}

extern "C" void kernel_launch(void* const* d_in, const int* in_sizes, int n_in,
                              void* d_out, int out_size, void* d_ws, size_t ws_size,
                              hipStream_t stream){
  (void)in_sizes; (void)n_in; (void)out_size; (void)ws_size;
  const float* obs  = (const float*)d_in[0];
  const float* W1   = (const float*)d_in[1];
  const float* b1   = (const float*)d_in[2];
  const float* W2   = (const float*)d_in[3];
  const float* b2   = (const float*)d_in[4];
  const float* W3   = (const float*)d_in[5];
  const float* b3   = (const float*)d_in[6];
  const float* W4   = (const float*)d_in[7];
  const float* b4   = (const float*)d_in[8];
  const float* Wih  = (const float*)d_in[9];
  const float* Whh  = (const float*)d_in[10];
  const float* bih  = (const float*)d_in[11];
  const float* Wm   = (const float*)d_in[12];
  const float* bm   = (const float*)d_in[13];
  const float* Wv   = (const float*)d_in[14];
  const float* bv   = (const float*)d_in[15];
  const float* eps0 = (const float*)d_in[16];
  const float* epss = (const float*)d_in[17];
  const float* nsy  = (const float*)d_in[18];

  char* ws = (char*)d_ws;
  float* gin   = (float*)(ws + 0);
  float* qmean = (float*)(ws + 6553600);
  float* qstd  = (float*)(ws + 6619136);
  float* klp   = (float*)(ws + 6684672);
  float* llp   = (float*)(ws + 6685184);

  float* out = (float*)d_out;

  hipLaunchKernelGGL(gin_kernel, dim3(TC*BC), dim3(256), 0, stream,
                     obs, Wih, bih, gin);
  hipLaunchKernelGGL(lstm_kernel, dim3(BC), dim3(256), 0, stream,
                     gin, Whh, Wm, bm, Wv, bv, qmean, qstd, klp);
  hipLaunchKernelGGL(enkf_kernel, dim3(BC), dim3(512), 0, stream,
                     obs, W1, b1, W2, b2, W3, b3, W4, b4,
                     eps0, epss, nsy, qmean, qstd, out + 1, llp);
  hipLaunchKernelGGL(final_kernel, dim3(1), dim3(128), 0, stream, klp, llp, out);
}